// Round 10
// baseline (91.866 us; speedup 1.0000x reference)
//
#include <hip/hip_runtime.h>

// CASSI forward A^T(A(x)) — R9: R2's dual-batched phase-1 loads + R8's
// exact-ideal phase-2 stores (LDS y2 exchange, band-per-wave float4 nt).
//
// out[b,l,m,n] = phi[l,m,n] * y2[b,m,n+2l]
// y2[b,m,c]    = sum_l phi[l,m,c-2l] * x[b,l,m,c-2l]   (valid 0<=c-2l<N)
//
// Evidence ladder:
//  R2: BOTH x and phi batched in regs (VGPR 88) -> 4.7 TB/s mixed, 81 µs,
//      but ragged 8B nt stores cost +24MB WRITE.
//  R7: select-on-load-result serialized loads (VGPR 64) -> 101 µs.
//  R8: x batched, phi still load->fma serialized (VGPR 76) -> 90.8 µs;
//      phase 2 verified WRITE exactly 229.4MB.
// R9 = R2 phase 1 (two pure clamped-address load batches, one
//      sched_barrier(0) after all 56 loads, post-batch select-zero on phi)
//      + R8 phase 2 unchanged. __syncthreads drains lgkm only, so global
//      loads stay in flight across it.

constexpr int L_BANDS = 28;
constexpr int M_DIM   = 256;
constexpr int N_DIM   = 256;
constexpr int SHIFT   = 2;
constexpr int N_OUT   = N_DIM + SHIFT * (L_BANDS - 1);  // 310
constexpr int NPAIR   = N_OUT / 2;                      // 155
constexpr int MN      = M_DIM * N_DIM;                  // 65536
constexpr int Y2PAD   = 352;                            // swz(309)=347 < 352
constexpr int UNITS   = 2 * L_BANDS;                    // 56 (row,band) units

typedef float v2f __attribute__((ext_vector_type(2)));
typedef float v4f __attribute__((ext_vector_type(4)));

// LDS skew: phase-2 reads stride ~4 words/lane; +w/8 spreads banks (~2-way,
// 1.9M conflict cycles aggregate ≈ 3 µs — acceptable).
__device__ __forceinline__ int swz(int w) { return w + (w >> 3); }

__global__ __launch_bounds__(320) void cassi_fwd_kernel(
    const float* __restrict__ x,
    const float* __restrict__ phi,
    float* __restrict__ out)
{
    __shared__ float y2s[2][Y2PAD];

    const int t  = threadIdx.x;
    const int b  = blockIdx.x >> 7;          // / (M_DIM/2)
    const int m0 = (blockIdx.x & 127) << 1;  // first of the block's 2 rows

    // ---------------- Phase 1: gather x*phi -> y2 (LDS) ----------------
    {
        const int r = (t >= 160) ? 1 : 0;
        const int p = t - 160 * r;
        if (p < NPAIR) {
            const int m  = m0 + r;
            const int c0 = p << 1;           // even dispersed column
            const float* xb = x   + b * (L_BANDS * MN) + m * N_DIM;
            const float* pb = phi +                      m * N_DIM;

            // Two pure load batches: clamped always-valid addresses, no
            // selects on results. All 56 loads in flight before any consume.
            v2f xr[L_BANDS];
            v2f pr[L_BANDS];
            #pragma unroll
            for (int l = 0; l < L_BANDS; ++l) {
                const int n0 = c0 - SHIFT * l;
                const int n0c = n0 < 0 ? 0 : (n0 > N_DIM - 2 ? N_DIM - 2 : n0);
                xr[l] = *(const v2f*)(xb + l * MN + n0c);
            }
            #pragma unroll
            for (int l = 0; l < L_BANDS; ++l) {
                const int n0 = c0 - SHIFT * l;
                const int n0c = n0 < 0 ? 0 : (n0 > N_DIM - 2 ? N_DIM - 2 : n0);
                pr[l] = *(const v2f*)(pb + l * MN + n0c);
            }
            __builtin_amdgcn_sched_barrier(0);

            // Consume: zero the phi operand for out-of-range bands
            // (post-batch select: garbage * 0 == 0).
            v2f acc = (v2f)(0.0f);
            #pragma unroll
            for (int l = 0; l < L_BANDS; ++l) {
                const int n0 = c0 - SHIFT * l;
                const bool valid = (unsigned)n0 < (unsigned)(N_DIM - 1);
                const v2f pv = valid ? pr[l] : (v2f)(0.0f);
                acc += xr[l] * pv;
            }
            const int s = swz(c0);           // even pairs stay adjacent
            y2s[r][s]     = acc.x;
            y2s[r][s + 1] = acc.y;
        }
    }
    __syncthreads();

    // ------- Phase 2: out = phi * gather(y2); aligned float4 nt stores ------
    // One (row, band) unit = one full 1KB-aligned band row (64 lanes x 16B)
    // -> WRITE_SIZE exactly ideal (verified R7/R8).
    const int wid = t >> 6;        // 5 waves
    const int q   = t & 63;
    const int n0  = q << 2;        // 16B-aligned quad base
    const float* pbase = phi + m0 * N_DIM + n0;
    float*       obase = out + b * (L_BANDS * MN) + m0 * N_DIM + n0;

    #pragma unroll
    for (int it = 0; it < 12; ++it) {
        const int u = wid + it * 5;          // (row,band) unit
        if (u < UNITS) {
            const int rr = (u >= L_BANDS) ? 1 : 0;
            const int l  = u - L_BANDS * rr;
            const int w  = n0 + SHIFT * l;   // dispersed col of n0
            const v4f p4 = *(const v4f*)(pbase + l * MN + rr * N_DIM);
            v4f y4;
            y4.x = y2s[rr][swz(w)];
            y4.y = y2s[rr][swz(w + 1)];
            y4.z = y2s[rr][swz(w + 2)];
            y4.w = y2s[rr][swz(w + 3)];
            __builtin_nontemporal_store(p4 * y4,
                                        (v4f*)(obase + l * MN + rr * N_DIM));
        }
    }
}

extern "C" void kernel_launch(void* const* d_in, const int* in_sizes, int n_in,
                              void* d_out, int out_size, void* d_ws, size_t ws_size,
                              hipStream_t stream) {
    const float* x   = (const float*)d_in[0];
    const float* phi = (const float*)d_in[1];
    float*       out = (float*)d_out;

    const int B = in_sizes[0] / (L_BANDS * MN);   // 32

    dim3 grid(B * (M_DIM / 2));  // one block per (b, row-pair): 4096 blocks
    dim3 block(320);             // phase1: 2x155 pair-threads; phase2: 5 waves
    cassi_fwd_kernel<<<grid, block, 0, stream>>>(x, phi, out);
}